// Round 8
// baseline (2800.007 us; speedup 1.0000x reference)
//
#include <hip/hip_runtime.h>
#include <cstddef>
#include <cstdint>

#define DM   128
#define NH   8
#define DP   16
#define SEQ  2048
#define BB   4
#define CK   128
#define NCH  (SEQ / CK)   // 16

typedef float f32x2 __attribute__((ext_vector_type(2)));

__device__ __forceinline__ float dot16(const float4 a[4], const float4 b[4]) {
  float s = 0.f;
#pragma unroll
  for (int i = 0; i < 4; ++i)
    s += a[i].x * b[i].x + a[i].y * b[i].y + a[i].z * b[i].z + a[i].w * b[i].w;
  return s;
}

// out[64 rows @ row0][128] = X @ W[128][128] + bias
// headsplit=1: store to [B,H,S,16] layout; else row-major [M,128]
__device__ __forceinline__ void gemm128_body(
    const float* __restrict__ X, const float* __restrict__ W,
    const float* __restrict__ bias, float* __restrict__ out,
    int row0, int headsplit)
{
  __shared__ float xs[64][DM];   // 32 KB
  const int t = threadIdx.x;
  {
    const float4* Xv = (const float4*)(X + (size_t)row0 * DM);
    float4* xsv = (float4*)&xs[0][0];
#pragma unroll
    for (int i = 0; i < 8; ++i) xsv[t + i * 256] = Xv[t + i * 256];
  }
  __syncthreads();
  const int cg = t & 31;   // cols cg*4 .. cg*4+3
  const int rg = t >> 5;   // rows rg*8 .. rg*8+7
  float acc[8][4];
#pragma unroll
  for (int i = 0; i < 8; ++i)
#pragma unroll
    for (int j = 0; j < 4; ++j) acc[i][j] = 0.f;

  for (int k = 0; k < DM; k += 4) {
    float4 w0 = *(const float4*)(W + (size_t)(k + 0) * DM + cg * 4);
    float4 w1 = *(const float4*)(W + (size_t)(k + 1) * DM + cg * 4);
    float4 w2 = *(const float4*)(W + (size_t)(k + 2) * DM + cg * 4);
    float4 w3 = *(const float4*)(W + (size_t)(k + 3) * DM + cg * 4);
#pragma unroll
    for (int i = 0; i < 8; ++i) {
      float4 xv = *(const float4*)(&xs[rg * 8 + i][k]);
      acc[i][0] += xv.x * w0.x + xv.y * w1.x + xv.z * w2.x + xv.w * w3.x;
      acc[i][1] += xv.x * w0.y + xv.y * w1.y + xv.z * w2.y + xv.w * w3.y;
      acc[i][2] += xv.x * w0.z + xv.y * w1.z + xv.z * w2.z + xv.w * w3.z;
      acc[i][3] += xv.x * w0.w + xv.y * w1.w + xv.z * w2.w + xv.w * w3.w;
    }
  }
  float4 bv = *(const float4*)(bias + cg * 4);
#pragma unroll
  for (int i = 0; i < 8; ++i) {
    int row = row0 + rg * 8 + i;
    float4 o;
    o.x = acc[i][0] + bv.x; o.y = acc[i][1] + bv.y;
    o.z = acc[i][2] + bv.z; o.w = acc[i][3] + bv.w;
    if (headsplit) {
      int b = row >> 11, s = row & (SEQ - 1);
      int col = cg * 4;
      int h = col >> 4, d = col & 15;
      *(float4*)(out + (((size_t)(b * NH + h) * SEQ + s) * DP + d)) = o;
    } else {
      *(float4*)(out + (size_t)row * DM + cg * 4) = o;
    }
  }
}

__global__ __launch_bounds__(256) void proj_kernel(
    const float* __restrict__ q, const float* __restrict__ k,
    const float* __restrict__ v, const float* __restrict__ W,
    const float* __restrict__ bias, float* __restrict__ ws)
{
  const float* X = (blockIdx.y == 0) ? q : (blockIdx.y == 1) ? k : v;
  float* out = ws + (size_t)blockIdx.y * ((size_t)BB * SEQ * DM);
  gemm128_body(X, W, bias, out, blockIdx.x * 64, 1);
}

__global__ __launch_bounds__(256) void dense_kernel(
    const float* __restrict__ ctx, const float* __restrict__ W,
    const float* __restrict__ bias, float* __restrict__ out)
{
  // buggy reshape [B,H,S,dp]->[B,S,128] without head transpose == flat [8192][128]
  gemm128_body(ctx, W, bias, out, blockIdx.x * 64, 0);
}

// 1 q-row per wave, 4 independent waves per block, no LDS, no barriers.
// R4 post-mortem: at VGPR=256 only ~1 wave/SIMD was resident (Occupancy 12%,
// VALUBusy 24%) -> pure load-latency serialization. Halving per-wave state
// (1 row: p=32, q=16, acc=16, staging=32 ~= 110 VGPR) with a hard cap via
// __launch_bounds__(256,4) doubles resident waves/SIMD to 4 -> 2x latency
// hiding. Lane owns adjacent keys (2*lane, 2*lane+1): 128B contiguous K/V
// loads per lane, float2 mask load, nt dwordx2 attn stores.
__global__ __launch_bounds__(256, 4) void attn_kernel(
    const float* __restrict__ qh, const float* __restrict__ kh,
    const float* __restrict__ vh, const float* __restrict__ mask,
    float* __restrict__ attn, float* __restrict__ ctx)
{
  const int t = threadIdx.x;
  const int lane = t & 63;
  const int w = t >> 6;            // wave 0..3
  const int bh = blockIdx.x >> 9;  // 0..31  (consecutive blocks share K/V in L2)
  const int qb = blockIdx.x & 511;
  const int b = bh >> 3;
  const int r = qb * 4 + w;        // this wave's q row

  const float4* K4 = (const float4*)(kh + (size_t)bh * SEQ * DP);
  const float4* V4 = (const float4*)(vh + (size_t)bh * SEQ * DP);
  const float* mp = mask + (size_t)b * SEQ;

  float4 q[4];
  {
    const float4* Q4 = (const float4*)(qh + ((size_t)bh * SEQ + r) * DP);
#pragma unroll
    for (int s = 0; s < 4; ++s) q[s] = Q4[s];
  }

  float p[2 * NCH];   // raw logits -> exp values, in registers

  // ---- QK^T: lane loads its own two adjacent K rows per chunk ----
#pragma unroll
  for (int cc = 0; cc < NCH; ++cc) {
    const float4* Ka = K4 + ((size_t)(cc * CK + 2 * lane)) * 4;
    float4 ka[4], kb[4];
#pragma unroll
    for (int s = 0; s < 4; ++s) { ka[s] = Ka[s]; kb[s] = Ka[4 + s]; }
    f32x2 mv = *(const f32x2*)(mp + cc * CK + 2 * lane);
    p[2 * cc]     = dot16(ka, q) * 0.25f + mv.x * -1e9f;
    p[2 * cc + 1] = dot16(kb, q) * 0.25f + mv.y * -1e9f;
  }

  // ---- softmax (wave-wide: 64 lanes x 32 keys = full 2048-key row) ----
  float mx = p[0];
#pragma unroll
  for (int j = 1; j < 2 * NCH; ++j) mx = fmaxf(mx, p[j]);
#pragma unroll
  for (int m = 1; m < 64; m <<= 1) mx = fmaxf(mx, __shfl_xor(mx, m));
  float sum = 0.f;
#pragma unroll
  for (int j = 0; j < 2 * NCH; ++j) { p[j] = __expf(p[j] - mx); sum += p[j]; }
#pragma unroll
  for (int m = 1; m < 64; m <<= 1) sum += __shfl_xor(sum, m);
  const float inv = 1.0f / sum;

  // ---- write normalized attention (coalesced nt dwordx2, from registers) ----
  {
    float* a0 = attn + ((size_t)bh * SEQ + r) * SEQ;
#pragma unroll
    for (int cc = 0; cc < NCH; ++cc) {
      f32x2 o;
      o.x = p[2 * cc] * inv;
      o.y = p[2 * cc + 1] * inv;
      __builtin_nontemporal_store(o, (f32x2*)(a0 + cc * CK + 2 * lane));
    }
  }

  // ---- PV: lane loads its own two adjacent V rows per chunk ----
  float4 acc[4];
#pragma unroll
  for (int s = 0; s < 4; ++s) acc[s] = make_float4(0.f, 0.f, 0.f, 0.f);
#pragma unroll
  for (int cc = 0; cc < NCH; ++cc) {
    const float4* Va = V4 + ((size_t)(cc * CK + 2 * lane)) * 4;
    float pa = p[2 * cc], pb = p[2 * cc + 1];
#pragma unroll
    for (int s = 0; s < 4; ++s) {
      float4 va = Va[s];
      float4 vb = Va[4 + s];
      acc[s].x += pa * va.x + pb * vb.x;
      acc[s].y += pa * va.y + pb * vb.y;
      acc[s].z += pa * va.z + pb * vb.z;
      acc[s].w += pa * va.w + pb * vb.w;
    }
  }
#pragma unroll
  for (int s = 0; s < 4; ++s) {
    acc[s].x *= inv; acc[s].y *= inv; acc[s].z *= inv; acc[s].w *= inv;
  }
  // butterfly-reduce ctx partials across the wave
#pragma unroll
  for (int m = 1; m < 64; m <<= 1) {
#pragma unroll
    for (int s = 0; s < 4; ++s) {
      acc[s].x += __shfl_xor(acc[s].x, m);
      acc[s].y += __shfl_xor(acc[s].y, m);
      acc[s].z += __shfl_xor(acc[s].z, m);
      acc[s].w += __shfl_xor(acc[s].w, m);
    }
  }
  if (lane == 0) {
    float4* c4 = (float4*)(ctx + ((size_t)bh * SEQ + r) * DP);
#pragma unroll
    for (int s = 0; s < 4; ++s) c4[s] = acc[s];
  }
}

extern "C" void kernel_launch(void* const* d_in, const int* in_sizes, int n_in,
                              void* d_out, int out_size, void* d_ws, size_t ws_size,
                              hipStream_t stream) {
  const float* q    = (const float*)d_in[0];
  const float* k    = (const float*)d_in[1];
  const float* v    = (const float*)d_in[2];
  const float* mask = (const float*)d_in[3];
  const float* wq_w = (const float*)d_in[4];
  const float* wq_b = (const float*)d_in[5];
  const float* dw   = (const float*)d_in[6];
  const float* db   = (const float*)d_in[7];

  float* ws  = (float*)d_ws;
  float* qh  = ws;                       // [B,H,S,16]
  float* kh  = ws + 1048576;
  float* vh  = ws + 2097152;
  float* ctx = ws + 3145728;             // [B,H,S,16] == flat [8192][128]

  float* out  = (float*)d_out;                     // [4,2048,128]
  float* attn = out + (size_t)BB * SEQ * DM;       // [4,8,2048,2048]

  proj_kernel<<<dim3(128, 3), 256, 0, stream>>>(q, k, v, wq_w, wq_b, ws);
  attn_kernel<<<dim3(16384), 256, 0, stream>>>(qh, kh, vh, mask, attn, ctx);
  dense_kernel<<<dim3(128), 256, 0, stream>>>(ctx, dw, db, out);
}

// Round 10
// 2349.002 us; speedup vs baseline: 1.1920x; 1.1920x over previous
//
#include <hip/hip_runtime.h>
#include <cstddef>
#include <cstdint>

#define DM   128
#define NH   8
#define DP   16
#define SEQ  2048
#define BB   4
#define CK   128
#define HALF 1024
#define NC2  (HALF / CK)   // 8 chunks per half-row

typedef float f32x2 __attribute__((ext_vector_type(2)));

__device__ __forceinline__ float dot16(const float4 a[4], const float4 b[4]) {
  float s = 0.f;
#pragma unroll
  for (int i = 0; i < 4; ++i)
    s += a[i].x * b[i].x + a[i].y * b[i].y + a[i].z * b[i].z + a[i].w * b[i].w;
  return s;
}

// out[64 rows @ row0][128] = X @ W[128][128] + bias
// headsplit=1: store to [B,H,S,16] layout; else row-major [M,128]
__device__ __forceinline__ void gemm128_body(
    const float* __restrict__ X, const float* __restrict__ W,
    const float* __restrict__ bias, float* __restrict__ out,
    int row0, int headsplit)
{
  __shared__ float xs[64][DM];   // 32 KB
  const int t = threadIdx.x;
  {
    const float4* Xv = (const float4*)(X + (size_t)row0 * DM);
    float4* xsv = (float4*)&xs[0][0];
#pragma unroll
    for (int i = 0; i < 8; ++i) xsv[t + i * 256] = Xv[t + i * 256];
  }
  __syncthreads();
  const int cg = t & 31;   // cols cg*4 .. cg*4+3
  const int rg = t >> 5;   // rows rg*8 .. rg*8+7
  float acc[8][4];
#pragma unroll
  for (int i = 0; i < 8; ++i)
#pragma unroll
    for (int j = 0; j < 4; ++j) acc[i][j] = 0.f;

  for (int k = 0; k < DM; k += 4) {
    float4 w0 = *(const float4*)(W + (size_t)(k + 0) * DM + cg * 4);
    float4 w1 = *(const float4*)(W + (size_t)(k + 1) * DM + cg * 4);
    float4 w2 = *(const float4*)(W + (size_t)(k + 2) * DM + cg * 4);
    float4 w3 = *(const float4*)(W + (size_t)(k + 3) * DM + cg * 4);
#pragma unroll
    for (int i = 0; i < 8; ++i) {
      float4 xv = *(const float4*)(&xs[rg * 8 + i][k]);
      acc[i][0] += xv.x * w0.x + xv.y * w1.x + xv.z * w2.x + xv.w * w3.x;
      acc[i][1] += xv.x * w0.y + xv.y * w1.y + xv.z * w2.y + xv.w * w3.y;
      acc[i][2] += xv.x * w0.z + xv.y * w1.z + xv.z * w2.z + xv.w * w3.z;
      acc[i][3] += xv.x * w0.w + xv.y * w1.w + xv.z * w2.w + xv.w * w3.w;
    }
  }
  float4 bv = *(const float4*)(bias + cg * 4);
#pragma unroll
  for (int i = 0; i < 8; ++i) {
    int row = row0 + rg * 8 + i;
    float4 o;
    o.x = acc[i][0] + bv.x; o.y = acc[i][1] + bv.y;
    o.z = acc[i][2] + bv.z; o.w = acc[i][3] + bv.w;
    if (headsplit) {
      int b = row >> 11, s = row & (SEQ - 1);
      int col = cg * 4;
      int h = col >> 4, d = col & 15;
      *(float4*)(out + (((size_t)(b * NH + h) * SEQ + s) * DP + d)) = o;
    } else {
      *(float4*)(out + (size_t)row * DM + cg * 4) = o;
    }
  }
}

__global__ __launch_bounds__(256) void proj_kernel(
    const float* __restrict__ q, const float* __restrict__ k,
    const float* __restrict__ v, const float* __restrict__ W,
    const float* __restrict__ bias, float* __restrict__ ws)
{
  const float* X = (blockIdx.y == 0) ? q : (blockIdx.y == 1) ? k : v;
  float* out = ws + (size_t)blockIdx.y * ((size_t)BB * SEQ * DM);
  gemm128_body(X, W, bias, out, blockIdx.x * 64, 1);
}

__global__ __launch_bounds__(256) void dense_kernel(
    const float* __restrict__ ctx, const float* __restrict__ W,
    const float* __restrict__ bias, float* __restrict__ out)
{
  // buggy reshape [B,H,S,dp]->[B,S,128] without head transpose == flat [8192][128]
  gemm128_body(ctx, W, bias, out, blockIdx.x * 64, 0);
}

// Half-row waves: each wave owns 1024 keys of one q-row -> p[16] (not p[32]),
// true VGPR demand ~100-120, capped via (256,3) (~170) so NO SPILLS (R8
// lesson: (256,4)'s 128 cap forced VGPR=64 + 2.4GB scratch traffic, 3x slower).
// Block = 4 waves = 2 rows x 2 halves. Cross-wave softmax (max, sum) and PV
// combine via tiny LDS with 3 whole-kernel barriers (not per-chunk).
// Lane owns adjacent keys (2*lane, 2*lane+1): contiguous 128B loads,
// f32x2 mask load, nt f32x2 attn stores.
__global__ __launch_bounds__(256, 3) void attn_kernel(
    const float* __restrict__ qh, const float* __restrict__ kh,
    const float* __restrict__ vh, const float* __restrict__ mask,
    float* __restrict__ attn, float* __restrict__ ctx)
{
  __shared__ float redm[2][2];     // [row-in-block][half] partial max
  __shared__ float reds[2][2];     // partial sum
  __shared__ float4 accx[2][4];    // half-1 PV partials

  const int t = threadIdx.x;
  const int lane = t & 63;
  const int w = t >> 6;            // wave 0..3
  const int rb = w >> 1;           // row-in-block 0..1
  const int h  = w & 1;            // key-half 0..1
  const int bh = blockIdx.x >> 10; // 0..31 (consecutive blocks share K/V in L2)
  const int qb = blockIdx.x & 1023;
  const int b  = bh >> 3;
  const int r  = qb * 2 + rb;      // this wave's q row

  const float4* K4 = (const float4*)(kh + ((size_t)bh * SEQ + h * HALF) * DP);
  const float4* V4 = (const float4*)(vh + ((size_t)bh * SEQ + h * HALF) * DP);
  const float* mp = mask + (size_t)b * SEQ + h * HALF;

  float4 q[4];
  {
    const float4* Q4 = (const float4*)(qh + ((size_t)bh * SEQ + r) * DP);
#pragma unroll
    for (int s = 0; s < 4; ++s) q[s] = Q4[s];
  }

  float p[2 * NC2];   // raw logits -> exp values, in registers (16)

  // ---- QK^T: lane loads its own two adjacent K rows per chunk ----
#pragma unroll
  for (int cc = 0; cc < NC2; ++cc) {
    const float4* Ka = K4 + ((size_t)(cc * CK + 2 * lane)) * 4;
    float4 ka[4], kb[4];
#pragma unroll
    for (int s = 0; s < 4; ++s) { ka[s] = Ka[s]; kb[s] = Ka[4 + s]; }
    f32x2 mv = *(const f32x2*)(mp + cc * CK + 2 * lane);
    p[2 * cc]     = dot16(ka, q) * 0.25f + mv.x * -1e9f;
    p[2 * cc + 1] = dot16(kb, q) * 0.25f + mv.y * -1e9f;
  }

  // ---- softmax: wave-local reduce, then cross-half exchange via LDS ----
  float mx = p[0];
#pragma unroll
  for (int j = 1; j < 2 * NC2; ++j) mx = fmaxf(mx, p[j]);
#pragma unroll
  for (int m = 1; m < 64; m <<= 1) mx = fmaxf(mx, __shfl_xor(mx, m));
  if (lane == 0) redm[rb][h] = mx;
  __syncthreads();
  mx = fmaxf(mx, redm[rb][h ^ 1]);          // global row max

  float sum = 0.f;
#pragma unroll
  for (int j = 0; j < 2 * NC2; ++j) { p[j] = __expf(p[j] - mx); sum += p[j]; }
#pragma unroll
  for (int m = 1; m < 64; m <<= 1) sum += __shfl_xor(sum, m);
  if (lane == 0) reds[rb][h] = sum;
  __syncthreads();
  const float inv = 1.0f / (reds[rb][0] + reds[rb][1]);   // global row sum

  // ---- write normalized attention (coalesced nt f32x2, from registers) ----
  {
    float* a0 = attn + ((size_t)bh * SEQ + r) * SEQ + h * HALF;
#pragma unroll
    for (int cc = 0; cc < NC2; ++cc) {
      f32x2 o;
      o.x = p[2 * cc] * inv;
      o.y = p[2 * cc + 1] * inv;
      __builtin_nontemporal_store(o, (f32x2*)(a0 + cc * CK + 2 * lane));
    }
  }

  // ---- PV: lane loads its own two adjacent V rows per chunk ----
  float4 acc[4];
#pragma unroll
  for (int s = 0; s < 4; ++s) acc[s] = make_float4(0.f, 0.f, 0.f, 0.f);
#pragma unroll
  for (int cc = 0; cc < NC2; ++cc) {
    const float4* Va = V4 + ((size_t)(cc * CK + 2 * lane)) * 4;
    float pa = p[2 * cc], pb = p[2 * cc + 1];
#pragma unroll
    for (int s = 0; s < 4; ++s) {
      float4 va = Va[s];
      float4 vb = Va[4 + s];
      acc[s].x += pa * va.x + pb * vb.x;
      acc[s].y += pa * va.y + pb * vb.y;
      acc[s].z += pa * va.z + pb * vb.z;
      acc[s].w += pa * va.w + pb * vb.w;
    }
  }
#pragma unroll
  for (int s = 0; s < 4; ++s) {
    acc[s].x *= inv; acc[s].y *= inv; acc[s].z *= inv; acc[s].w *= inv;
  }
  // butterfly-reduce within wave (every lane ends with the half-row total)
#pragma unroll
  for (int m = 1; m < 64; m <<= 1) {
#pragma unroll
    for (int s = 0; s < 4; ++s) {
      acc[s].x += __shfl_xor(acc[s].x, m);
      acc[s].y += __shfl_xor(acc[s].y, m);
      acc[s].z += __shfl_xor(acc[s].z, m);
      acc[s].w += __shfl_xor(acc[s].w, m);
    }
  }
  // combine halves via LDS, half-0 wave stores ctx row
  if (h == 1 && lane < 4) accx[rb][lane] = acc[lane];
  __syncthreads();
  if (h == 0 && lane < 4) {
    float4 o = acc[lane];
    float4 pj = accx[rb][lane];
    o.x += pj.x; o.y += pj.y; o.z += pj.z; o.w += pj.w;
    ((float4*)(ctx + ((size_t)bh * SEQ + r) * DP))[lane] = o;
  }
}

extern "C" void kernel_launch(void* const* d_in, const int* in_sizes, int n_in,
                              void* d_out, int out_size, void* d_ws, size_t ws_size,
                              hipStream_t stream) {
  const float* q    = (const float*)d_in[0];
  const float* k    = (const float*)d_in[1];
  const float* v    = (const float*)d_in[2];
  const float* mask = (const float*)d_in[3];
  const float* wq_w = (const float*)d_in[4];
  const float* wq_b = (const float*)d_in[5];
  const float* dw   = (const float*)d_in[6];
  const float* db   = (const float*)d_in[7];

  float* ws  = (float*)d_ws;
  float* qh  = ws;                       // [B,H,S,16]
  float* kh  = ws + 1048576;
  float* vh  = ws + 2097152;
  float* ctx = ws + 3145728;             // [B,H,S,16] == flat [8192][128]

  float* out  = (float*)d_out;                     // [4,2048,128]
  float* attn = out + (size_t)BB * SEQ * DM;       // [4,8,2048,2048]

  proj_kernel<<<dim3(128, 3), 256, 0, stream>>>(q, k, v, wq_w, wq_b, ws);
  attn_kernel<<<dim3(32768), 256, 0, stream>>>(qh, kh, vh, mask, attn, ctx);
  dense_kernel<<<dim3(128), 256, 0, stream>>>(ctx, dw, db, out);
}